// Round 1
// baseline (306.719 us; speedup 1.0000x reference)
//
#include <hip/hip_runtime.h>
#include <stdint.h>

// DetectPeaksTM: per row of nt=8192 fp32, x=|xcorr|, sliding max window K=301
// (pad 150, same-size), scores = x where x==windowmax else 0, top-2 (score, idx).
// Outputs concatenated: [nrows*2] f32 scores, then [nrows*2] indices. Harness
// reads whole d_out as float32 -> indices written as float values (exact).
//
// Structure: one block (256 thr) per row.
//  P1: coalesced float4 load -> abs -> regs + LDS copy xs[]; segment(32-elem)
//      maxes m[256] via 8-lane shuffle reduction (lanes 8k..8k+7 hold one seg).
//  P2: candidate = element equal to its own segment max (segment is inside the
//      +-150 window, so every true peak is a candidate). ~256 cands/row.
//  P3: exact window check per candidate: interior full segments via m[],
//      boundary partials (<=32 elems each) via xs[].
//  P4: top-2 via monotone key (bits(v)<<32)|(8191-t)  (value desc, idx asc on
//      ties -- matches jax.lax.top_k stable ordering), wave shuffle + LDS.

#define NT 8192
#define RADIUS 150
#define NSEG 256
#define NTHREADS 256
#define CAND_CAP 1024

__global__ __launch_bounds__(256) void detect_peaks_kernel(
    const float* __restrict__ x, float* __restrict__ out, int nrows)
{
    const int row = blockIdx.x;
    const int tid = threadIdx.x;

    __shared__ __align__(16) float xs[NT];
    __shared__ float m[NSEG];
    __shared__ int cand[CAND_CAP];
    __shared__ int cnt;
    __shared__ unsigned long long wred[8];

    if (tid == 0) cnt = 0;

    const float4* g = (const float4*)(x + (size_t)row * NT);
    float4 vv[8];
#pragma unroll
    for (int it = 0; it < 8; ++it) {
        float4 v = g[it * 256 + tid];
        v.x = fabsf(v.x); v.y = fabsf(v.y); v.z = fabsf(v.z); v.w = fabsf(v.w);
        vv[it] = v;
        float cm = fmaxf(fmaxf(v.x, v.y), fmaxf(v.z, v.w));
        // lanes 8k..8k+7 (same tid>>3) hold the 8 float4 chunks of one segment
        cm = fmaxf(cm, __shfl_xor(cm, 1));
        cm = fmaxf(cm, __shfl_xor(cm, 2));
        cm = fmaxf(cm, __shfl_xor(cm, 4));
        const int c = it * 256 + tid;
        ((float4*)xs)[c] = v;
        if ((tid & 7) == 0) m[c >> 3] = cm;
    }
    __syncthreads();

    // candidate detection from registers (exact float equality: same values,
    // max is exact, so bitwise-identical)
#pragma unroll
    for (int it = 0; it < 8; ++it) {
        const int c = it * 256 + tid;
        const float ms = m[c >> 3];
        const float4 v = vv[it];
        const int base = c * 4;
        if (v.x == ms) { int p = atomicAdd(&cnt, 1); if (p < CAND_CAP) cand[p] = base + 0; }
        if (v.y == ms) { int p = atomicAdd(&cnt, 1); if (p < CAND_CAP) cand[p] = base + 1; }
        if (v.z == ms) { int p = atomicAdd(&cnt, 1); if (p < CAND_CAP) cand[p] = base + 2; }
        if (v.w == ms) { int p = atomicAdd(&cnt, 1); if (p < CAND_CAP) cand[p] = base + 3; }
    }
    __syncthreads();

    const int ncand = min(cnt, CAND_CAP);
    unsigned long long k1 = 0ull, k2 = 0ull;

    for (int k = tid; k < ncand; k += NTHREADS) {
        const int t = cand[k];
        const float v = xs[t];
        const int l = max(t - RADIUS, 0);
        const int r = min(t + RADIUS, NT - 1);
        const int il = l >> 5, ir = r >> 5;   // il < ir always (window >= 151)
        float wmax = 0.0f;                    // all values >= 0
        for (int s = il + 1; s < ir; ++s) wmax = fmaxf(wmax, m[s]);
        const int le = (il << 5) + 32;
        for (int u = l; u < le; ++u) wmax = fmaxf(wmax, xs[u]);
        const int rs = ir << 5;
        for (int u = rs; u <= r; ++u) wmax = fmaxf(wmax, xs[u]);
        if (v >= wmax) {
            const unsigned long long key =
                ((unsigned long long)__float_as_uint(v) << 32) |
                (unsigned)(NT - 1 - t);
            if (key > k1) { k2 = k1; k1 = key; }
            else if (key > k2) { k2 = key; }
        }
    }

    // wave (64-lane) top-2 reduction
#pragma unroll
    for (int off = 32; off >= 1; off >>= 1) {
        unsigned long long o1 = __shfl_down(k1, off);
        unsigned long long o2 = __shfl_down(k2, off);
        unsigned long long hi = (k1 > o1) ? k1 : o1;
        unsigned long long lo = (k1 > o1) ? o1 : k1;
        unsigned long long s2 = (k2 > o2) ? k2 : o2;
        k1 = hi;
        k2 = (lo > s2) ? lo : s2;
    }
    const int wave = tid >> 6;
    if ((tid & 63) == 0) { wred[wave * 2] = k1; wred[wave * 2 + 1] = k2; }
    __syncthreads();

    if (tid == 0) {
        unsigned long long a1 = wred[0], a2 = wred[1];
        for (int w = 1; w < 4; ++w) {
            unsigned long long o1 = wred[w * 2], o2 = wred[w * 2 + 1];
            unsigned long long hi = (a1 > o1) ? a1 : o1;
            unsigned long long lo = (a1 > o1) ? o1 : a1;
            unsigned long long s2 = (a2 > o2) ? a2 : o2;
            a1 = hi;
            a2 = (lo > s2) ? lo : s2;
        }
        float s1v, s2v; int i1, i2;
        if (a1 == 0ull) { s1v = 0.0f; i1 = 0; }  // never in practice
        else {
            s1v = __uint_as_float((unsigned)(a1 >> 32));
            i1 = (NT - 1) - (int)(a1 & 0xffffffffull);
        }
        if (a2 == 0ull) {  // <2 peaks: second top-k entry is first zero score
            s2v = 0.0f;
            i2 = (i1 == 0) ? 1 : 0;
        } else {
            s2v = __uint_as_float((unsigned)(a2 >> 32));
            i2 = (NT - 1) - (int)(a2 & 0xffffffffull);
        }
        out[row * 2 + 0] = s1v;
        out[row * 2 + 1] = s2v;
        float* oi = out + (size_t)nrows * 2;
        oi[row * 2 + 0] = (float)i1;
        oi[row * 2 + 1] = (float)i2;
    }
}

extern "C" void kernel_launch(void* const* d_in, const int* in_sizes, int n_in,
                              void* d_out, int out_size, void* d_ws, size_t ws_size,
                              hipStream_t stream) {
    const float* x = (const float*)d_in[0];
    // d_in[1] = nlag (unused by the reference)
    float* out = (float*)d_out;
    const int nrows = in_sizes[0] / NT;  // 32*3*64 = 6144
    detect_peaks_kernel<<<nrows, NTHREADS, 0, stream>>>(x, out, nrows);
}